// Round 2
// baseline (435.684 us; speedup 1.0000x reference)
//
#include <hip/hip_runtime.h>
#include <math.h>
#include <stdint.h>

#define EPS 1e-6f

constexpr int B = 8, C = 3, H = 720, W = 1280;
constexpr int PAD = 20;           // absorbs left out-of-bounds targets (d in [0,20))
constexpr int SZ  = 1308;         // W + PAD + slack for x1==W zero-weight target; mult of 4
constexpr int NT  = 320;          // 5 waves; each thread owns 2 float2 column pairs
// log2(1.414) in double precision
constexpr float K_LOG2 = 0.49978254377554356f;

// Native LDS f32 atomic add (fire-and-forget). hipcc's atomicAdd(float*) on
// shared memory expands to a ds_cmpst CAS loop (denormal-safety lowering) --
// measured 315 us vs 70 us baseline, VALUBusy 1.9% (latency-bound retries).
// ds_add_f32 is single-issue, no return, HW-serialized on collisions.
// OFF is a compile-time byte offset folded into the DS immediate.
template <int OFF>
__device__ __forceinline__ void lds_fadd(uint32_t addr, float v) {
    asm volatile("ds_add_f32 %0, %1 offset:%2" :: "v"(addr), "v"(v), "i"(OFF));
}

// One block per (b, y) row. Forward SCATTER: each source pixel contributes to
// exactly 2 outputs (1-D tent), so 2*W accumulator updates per row instead of
// the gather's 25*W tent evaluations. SoA accumulators in one LDS block so the
// 8 adds of one splat share a single address VGPR + offset immediates.
// Left pad of 20 absorbs OOB targets (never read back) == reference's valid
// mask. Reference's global 1.414^(-dmin) factor cancels in res/mask.
__global__ __launch_bounds__(NT) void splat_kernel(const float* __restrict__ im,
                                                   const float* __restrict__ disp,
                                                   float* __restrict__ out) {
    __shared__ __attribute__((aligned(16))) float smem[4 * SZ];
    float* const s0 = smem;
    float* const s1 = smem + SZ;
    float* const s2 = smem + 2 * SZ;
    float* const sw = smem + 3 * SZ;

    const int row = blockIdx.x;   // 0 .. B*H-1
    const int b = row / H;
    const int y = row - b * H;
    const int t = (int)threadIdx.x;

    const float* __restrict__ dr  = disp + (size_t)row * W;
    const float* __restrict__ im0 = im + ((size_t)(b * C + 0) * H + y) * W;
    const float* __restrict__ im1 = im + ((size_t)(b * C + 1) * H + y) * W;
    const float* __restrict__ im2 = im + ((size_t)(b * C + 2) * H + y) * W;

    // ---- issue global loads early (float2 = 8 B/lane, coalesced); latency
    //      hides under the LDS zero-init below ----
    const float2 dA  = ((const float2*)dr )[t];
    const float2 dB  = ((const float2*)dr )[t + NT];
    const float2 c0A = ((const float2*)im0)[t];
    const float2 c0B = ((const float2*)im0)[t + NT];
    const float2 c1A = ((const float2*)im1)[t];
    const float2 c1B = ((const float2*)im1)[t + NT];
    const float2 c2A = ((const float2*)im2)[t];
    const float2 c2B = ((const float2*)im2)[t + NT];

    // ---- zero accumulators (b128 writes) ----
    {
        float4* z = (float4*)smem;
        const float4 zero4 = make_float4(0.f, 0.f, 0.f, 0.f);
        for (int i = t; i < SZ; i += NT) z[i] = zero4;   // 4*SZ floats == SZ float4
    }
    __syncthreads();

    // ---- scatter: each source pixel splats into 2 slots of 4 SoA arrays ----
    auto splat = [&](int x, float d, float v0, float v1, float v2) {
        const float w   = exp2f(K_LOG2 * d);   // 1.414^d
        const float tx  = (float)x - d;        // target x (flow is -d, y-flow = 0)
        const float x0f = floorf(tx);
        const float fc  = tx - x0f;            // in [0,1)
        const int   i   = (int)x0f + PAD;      // >= 0 since d < 20; <= W-1+PAD
        const float wb  = w * fc;              // weight at ceil  (ref's wc)
        const float wa  = w - wb;              // weight at floor (ref's wa)
        const uint32_t a = (uint32_t)(uintptr_t)&s0[i];  // LDS byte offset
        lds_fadd<0>(a, v0 * wa);
        lds_fadd<4>(a, v0 * wb);
        lds_fadd<4 * SZ>(a, v1 * wa);
        lds_fadd<4 * SZ + 4>(a, v1 * wb);
        lds_fadd<8 * SZ>(a, v2 * wa);
        lds_fadd<8 * SZ + 4>(a, v2 * wb);
        lds_fadd<12 * SZ>(a, wa);
        lds_fadd<12 * SZ + 4>(a, wb);
    };
    splat(2 * t,              dA.x, c0A.x, c1A.x, c2A.x);
    splat(2 * t + 1,          dA.y, c0A.y, c1A.y, c2A.y);
    splat(2 * t + 2 * NT,     dB.x, c0B.x, c1B.x, c2B.x);
    splat(2 * t + 2 * NT + 1, dB.y, c0B.y, c1B.y, c2B.y);

    // Inline-asm DS ops are invisible to the compiler's waitcnt tracking:
    // drain them explicitly before the barrier.
    asm volatile("s_waitcnt lgkmcnt(0)" ::: "memory");
    __syncthreads();

    // ---- normalize + store (float2, coalesced; v_rcp_f32 ~1 ulp) ----
    float* __restrict__ o0 = out + ((size_t)(b * C + 0) * H + y) * W;
    float* __restrict__ o1 = out + ((size_t)(b * C + 1) * H + y) * W;
    float* __restrict__ o2 = out + ((size_t)(b * C + 2) * H + y) * W;
    {
        const float2 q0 = *(const float2*)&s0[2 * t + PAD];
        const float2 q1 = *(const float2*)&s1[2 * t + PAD];
        const float2 q2 = *(const float2*)&s2[2 * t + PAD];
        const float2 qw = *(const float2*)&sw[2 * t + PAD];
        const float ix = __builtin_amdgcn_rcpf(fmaxf(qw.x, EPS));
        const float iy = __builtin_amdgcn_rcpf(fmaxf(qw.y, EPS));
        ((float2*)o0)[t] = make_float2(q0.x * ix, q0.y * iy);
        ((float2*)o1)[t] = make_float2(q1.x * ix, q1.y * iy);
        ((float2*)o2)[t] = make_float2(q2.x * ix, q2.y * iy);
    }
    {
        const float2 q0 = *(const float2*)&s0[2 * t + 2 * NT + PAD];
        const float2 q1 = *(const float2*)&s1[2 * t + 2 * NT + PAD];
        const float2 q2 = *(const float2*)&s2[2 * t + 2 * NT + PAD];
        const float2 qw = *(const float2*)&sw[2 * t + 2 * NT + PAD];
        const float ix = __builtin_amdgcn_rcpf(fmaxf(qw.x, EPS));
        const float iy = __builtin_amdgcn_rcpf(fmaxf(qw.y, EPS));
        ((float2*)o0)[t + NT] = make_float2(q0.x * ix, q0.y * iy);
        ((float2*)o1)[t + NT] = make_float2(q1.x * ix, q1.y * iy);
        ((float2*)o2)[t + NT] = make_float2(q2.x * ix, q2.y * iy);
    }
}

extern "C" void kernel_launch(void* const* d_in, const int* in_sizes, int n_in,
                              void* d_out, int out_size, void* d_ws, size_t ws_size,
                              hipStream_t stream) {
    const float* im   = (const float*)d_in[0];
    const float* disp = (const float*)d_in[1];
    float* out = (float*)d_out;
    (void)d_ws; (void)ws_size;

    splat_kernel<<<B * H, NT, 0, stream>>>(im, disp, out);
}

// Round 5
// 188.423 us; speedup vs baseline: 2.3123x; 2.3123x over previous
//
#include <hip/hip_runtime.h>
#include <math.h>

#define EPS 1e-6f

constexpr int B = 8, C = 3, H = 720, W = 1280;
constexpr int OPL = 5;          // outputs per lane: 256 * 5 == 1280 == W
constexpr int WIN = OPL + 20;   // d in [0,20) -> 25-source shared window per lane
constexpr int WP  = W + 32;     // padded row length (window overrun + slack)
// log2(1.414) in double precision
constexpr float K_LOG2 = 0.49978254377554356f;

typedef float v2f __attribute__((ext_vector_type(2)));

// One block per (b, y) row. Atomic-free gather, 5 outputs per lane.
// PROVEN round-0 structure (passed @ 70us/dispatch). This round changes ONLY
// register math: (1) channel-packed v2f accumulators -> v_pk_fma_f32 (4 FMAs
// -> 2 packed per (j,k)); (2) divide -> v_rcp_f32 (proven r1/r2).
// LDS atomics measured lane-serialized (~210cyc/wave-instr, r1/r2) -> scatter
// is structurally slow on gfx950; gather stays.
// Reference's global 1.414^(-dmin) factor cancels in res/mask (dmin ~ 2.7e-6
// for 7.37M uniform[0,20) samples); omitting it perturbs w by <1e-6 relative.
__global__ __launch_bounds__(256) void gather_kernel(const float* __restrict__ im,
                                                     const float* __restrict__ disp,
                                                     float* __restrict__ out) {
    __shared__ float s0[WP], s1[WP], s2[WP], sw[WP], stx[WP];

    const int row = blockIdx.x;  // 0 .. B*H-1
    const int b = row / H;
    const int y = row - b * H;

    const float* __restrict__ dr  = disp + (size_t)row * W;
    const float* __restrict__ im0 = im + ((size_t)(b * C + 0) * H + y) * W;
    const float* __restrict__ im1 = im + ((size_t)(b * C + 1) * H + y) * W;
    const float* __restrict__ im2 = im + ((size_t)(b * C + 2) * H + y) * W;

    // ---- stage premultiplied {im*w, w} and tx into LDS (coalesced) ----
    for (int x = threadIdx.x; x < WP; x += 256) {
        if (x < W) {
            float d = dr[x];
            float w = exp2f(K_LOG2 * d);     // 1.414^d
            stx[x] = (float)x - d;
            s0[x] = im0[x] * w;
            s1[x] = im1[x] * w;
            s2[x] = im2[x] * w;
            sw[x] = w;
        } else {
            stx[x] = -1.0e9f;                // tent weight -> 0
            s0[x] = 0.f; s1[x] = 0.f; s2[x] = 0.f; sw[x] = 0.f;
        }
    }
    __syncthreads();

    // ---- gather: lane handles outputs [base, base+OPL) ----
    const int base = (int)threadIdx.x * OPL;
    const float fx0 = (float)base;
    v2f a01[OPL], a23[OPL];                  // {c0,c1} and {c2,wsum} accums
    #pragma unroll
    for (int k = 0; k < OPL; ++k) {
        a01[k] = (v2f){0.f, 0.f};
        a23[k] = (v2f){0.f, 0.f};
    }

    #pragma unroll 5
    for (int j = 0; j < WIN; ++j) {
        float tx = stx[base + j];
        float u  = tx - fx0;                 // tx relative to first output
        const v2f v01 = {s0[base + j], s1[base + j]};
        const v2f v23 = {s2[base + j], sw[base + j]};
        #pragma unroll
        for (int k = 0; k < OPL; ++k) {
            // tent weight: matches ref's wa (floor(tx)==x) / wc (floor(tx)==x-1)
            float bw = fmaxf(1.0f - fabsf(u - (float)k), 0.0f);
            a01[k] += v01 * bw;              // v_pk_fma_f32 candidates
            a23[k] += v23 * bw;
        }
    }
    __syncthreads();

    // ---- normalize, stage to LDS (reuse s0..s2), coalesced store ----
    #pragma unroll
    for (int k = 0; k < OPL; ++k) {
        float inv = __builtin_amdgcn_rcpf(fmaxf(a23[k].y, EPS));
        s0[base + k] = a01[k].x * inv;
        s1[base + k] = a01[k].y * inv;
        s2[base + k] = a23[k].x * inv;
    }
    __syncthreads();

    float* __restrict__ o0 = out + ((size_t)(b * C + 0) * H + y) * W;
    float* __restrict__ o1 = out + ((size_t)(b * C + 1) * H + y) * W;
    float* __restrict__ o2 = out + ((size_t)(b * C + 2) * H + y) * W;
    for (int x = threadIdx.x; x < W; x += 256) {
        o0[x] = s0[x];
        o1[x] = s1[x];
        o2[x] = s2[x];
    }
}

extern "C" void kernel_launch(void* const* d_in, const int* in_sizes, int n_in,
                              void* d_out, int out_size, void* d_ws, size_t ws_size,
                              hipStream_t stream) {
    const float* im   = (const float*)d_in[0];
    const float* disp = (const float*)d_in[1];
    float* out = (float*)d_out;
    (void)d_ws; (void)ws_size;

    gather_kernel<<<B * H, 256, 0, stream>>>(im, disp, out);
}